// Round 16
// baseline (721.726 us; speedup 1.0000x reference)
//
#include <hip/hip_runtime.h>
#include <hip/hip_bf16.h>

// ROUND 16 — FP32-OUTPUT PIPELINE.
// Root-cause theory (R15 staircase decode): d_out is FLOAT32 (reference
// returns float32; harness header: "else float*"). All prior rounds wrote
// bf16 into a float32 buffer -> read[i] ~= write[2i+1] (high-half aliasing),
// which retro-explains every print R0-R15, including the decorrelated
// 0.17-0.22 failure band and the bit-identical repeats per function.
// Math interpretation (vetted across R2/R12 implementations):
//   enc [seq][batch][dim] C-order; z = x @ W with W[d*256+e]; dict-order
//   bias/proj; logit = proj . tanh(z + bias); softmax over seq per batch;
//   vectors[b][d] = sum_s p[s,b] * enc[s][b][d].
// Outputs (float32): [0:16384) vectors [1][64][256]; [16384:278528) attn [64][4096].

#define R16_SEQ 4096
#define R16_NB 64
#define R16_H2 256

// ===== A: logits. One block per (s, bq); 16 batch-rows of one s =============
__global__ void r16_logits(const float* enc, const float* W,
                           const float* bias, const float* proj,
                           float* attnS) {
    __shared__ float encL[16][R16_H2];
    __shared__ float vL[16][R16_H2];
    __shared__ float part2[16][4];
    const int t  = threadIdx.x;          // 0..255 = e
    const int s  = blockIdx.x >> 2;
    const int bq = blockIdx.x & 3;

    for (int i = 0; i < 16; ++i) {
        encL[i][t] = enc[((size_t)s * R16_NB + bq * 16 + i) * R16_H2 + t];
    }
    __syncthreads();

    float z[16];
#pragma unroll
    for (int r = 0; r < 16; ++r) z[r] = 0.0f;

    for (int d = 0; d < R16_H2; ++d) {
        float w = W[d * R16_H2 + t];     // W[d][e]
#pragma unroll
        for (int r = 0; r < 16; ++r) z[r] = fmaf(encL[r][d], w, z[r]);
    }

    const float bv = bias[t];
    const float pv = proj[t];
#pragma unroll
    for (int r = 0; r < 16; ++r) vL[r][t] = pv * tanhf(z[r] + bv);
    __syncthreads();

    if (t < 64) {
        int r = t >> 2, seg = t & 3;
        float a = 0.0f;
        for (int j = 0; j < 64; ++j) a += vL[r][seg * 64 + j];
        part2[r][seg] = a;
    }
    __syncthreads();
    if (t < 16) {
        attnS[(size_t)(bq * 16 + t) * R16_SEQ + s] =
            part2[t][0] + part2[t][1] + part2[t][2] + part2[t][3];
    }
}

// ===== B: softmax over s for each b; writes float32 attn output =============
__global__ void r16_softmax(const float* attnS, float* out_attn) {
    __shared__ float sL[R16_SEQ];
    __shared__ float red[256];
    const int b = blockIdx.x;
    const int t = threadIdx.x;

    float lm = -1e30f;
    for (int s = t; s < R16_SEQ; s += 256) {
        float v = attnS[(size_t)b * R16_SEQ + s];
        sL[s] = v;
        lm = fmaxf(lm, v);
    }
    red[t] = lm;
    __syncthreads();
    for (int h = 128; h > 0; h >>= 1) {
        if (t < h) red[t] = fmaxf(red[t], red[t + h]);
        __syncthreads();
    }
    const float gmax = red[0];
    __syncthreads();

    float ls = 0.0f;
    for (int s = t; s < R16_SEQ; s += 256) {
        float e = __expf(sL[s] - gmax);
        sL[s] = e;
        ls += e;
    }
    red[t] = ls;
    __syncthreads();
    for (int h = 128; h > 0; h >>= 1) {
        if (t < h) red[t] += red[t + h];
        __syncthreads();
    }
    const float inv = 1.0f / red[0];

    for (int s = t; s < R16_SEQ; s += 256) {
        out_attn[(size_t)b * R16_SEQ + s] = sL[s] * inv;
    }
}

// ===== C: partial weighted sums over s-chunks of 256, enc [s][b][d] =========
__global__ void r16_wsum(const float* enc, const float* out_attn,
                         float* partials) {
    __shared__ float wl[256];
    const int b = blockIdx.x & 63;
    const int c = blockIdx.x >> 6;       // 0..15
    const int t = threadIdx.x;           // = d
    wl[t] = out_attn[(size_t)b * R16_SEQ + c * 256 + t];
    __syncthreads();
    float acc = 0.0f;
    for (int si = 0; si < 256; ++si) {
        acc = fmaf(wl[si],
                   enc[((size_t)(c * 256 + si) * R16_NB + b) * R16_H2 + t],
                   acc);
    }
    partials[((size_t)c * R16_NB + b) * R16_H2 + t] = acc;
}

// ===== D: final reduce over the 16 chunks; float32 vectors out ==============
__global__ void r16_reduce(const float* partials, float* out_vec) {
    const int b = blockIdx.x;
    const int t = threadIdx.x;           // = d
    float a = 0.0f;
    for (int c = 0; c < 16; ++c)
        a += partials[((size_t)c * R16_NB + b) * R16_H2 + t];
    out_vec[(size_t)b * R16_H2 + t] = a;
}

extern "C" void kernel_launch(void* const* d_in, const int* in_sizes, int n_in,
                              void* d_out, int out_size, void* d_ws, size_t ws_size,
                              hipStream_t stream) {
    const float* enc  = (const float*)d_in[0];
    const float* W    = (const float*)d_in[1];
    const float* bias = (const float*)d_in[2];
    const float* proj = (const float*)d_in[3];

    float* out      = (float*)d_out;                 // FLOAT32 output buffer
    float* out_vec  = out;                           // [1][64][256] = 16384
    float* out_attn = out + R16_NB * R16_H2;         // [64][4096]  = 262144

    char* ws = (char*)d_ws;
    float* attnS    = (float*)ws;                    // 1 MiB fp32 logits [b][s]
    float* partials = (float*)(ws + (1u << 20));     // 1 MiB fp32 [16][64][256]

    hipLaunchKernelGGL(r16_logits,  dim3(R16_SEQ * 4), dim3(256), 0, stream,
                       enc, W, bias, proj, attnS);
    hipLaunchKernelGGL(r16_softmax, dim3(R16_NB),      dim3(256), 0, stream,
                       attnS, out_attn);
    hipLaunchKernelGGL(r16_wsum,    dim3(16 * R16_NB), dim3(256), 0, stream,
                       enc, out_attn, partials);
    hipLaunchKernelGGL(r16_reduce,  dim3(R16_NB),      dim3(256), 0, stream,
                       partials, out_vec);
}

// Round 17
// 130.898 us; speedup vs baseline: 5.5137x; 5.5137x over previous
//
#include <hip/hip_runtime.h>
#include <hip/hip_bf16.h>

#define SEQ 4096
#define NB 64
#define H2 256
#define MROWS (SEQ * NB)   // 262144

typedef short bf16x8 __attribute__((ext_vector_type(8)));
typedef int   i32x4  __attribute__((ext_vector_type(4)));
typedef float f32x4  __attribute__((ext_vector_type(4)));

__device__ __forceinline__ float fast_tanh(float x) {
    // tanh(x) = 1 - 2/(exp(2x)+1); saturates correctly at +-inf
    float e = __expf(2.0f * x);
    return 1.0f - 2.0f * __builtin_amdgcn_rcpf(e + 1.0f);
}

// -------- pack W (fp32 [256][256] d-major) -> bf16 MFMA B-fragment order ----
// Wp[((kk*16+n)*64 + l)*8 + i] = bf16(W[(kk*32 + 8*(l>>4) + i)*256 + n*16 + (l&15)])
__global__ __launch_bounds__(256)
void pack_w_kernel(const float* __restrict__ W, __hip_bfloat16* __restrict__ Wp) {
    int t = blockIdx.x * 256 + threadIdx.x;   // 0..8191
    int l  = t & 63;
    int n  = (t >> 6) & 15;
    int kk = t >> 10;
    int e  = n * 16 + (l & 15);
    int d0 = kk * 32 + 8 * (l >> 4);
    union { __hip_bfloat16 h[8]; i32x4 v; } cv;
#pragma unroll
    for (int i = 0; i < 8; ++i) cv.h[i] = __float2bfloat16(W[(d0 + i) * H2 + e]);
    *reinterpret_cast<i32x4*>(&Wp[(size_t)t * 8]) = cv.v;
}

// -------- fused MFMA GEMM + tanh + proj-dot -> fp32 logits attnS[s*64+b] ----
__global__ __launch_bounds__(256, 2)
void mfma_logits_kernel(const float* __restrict__ enc,
                        const __hip_bfloat16* __restrict__ Wp,
                        const float* __restrict__ bias,
                        const float* __restrict__ proj,
                        float* __restrict__ attnS) {
    __shared__ __hip_bfloat16 aT[2][128][40];   // 128 rows x 32 d (pad->40)
    __shared__ __hip_bfloat16 wT[2][8192];      // 16 KiB W-chunk per K-step

    const int tid  = threadIdx.x;
    const int lane = tid & 63;
    const int w    = tid >> 6;
    const long r0  = (long)blockIdx.x * 128;

    f32x4 acc[2][16];
#pragma unroll
    for (int rt = 0; rt < 2; ++rt)
#pragma unroll
        for (int n = 0; n < 16; ++n) acc[rt][n] = (f32x4)(0.0f);

    // ---- prologue: stage K-chunk 0 ----
#pragma unroll
    for (int it = 0; it < 4; ++it) {
        int q = it * 256 + tid;
        int row = q >> 3;
        int dc = (q & 7) * 4;
        float4 v = *reinterpret_cast<const float4*>(&enc[(r0 + row) * H2 + dc]);
        union { __hip_bfloat16 h[4]; uint2 u; } cv;
        cv.h[0] = __float2bfloat16(v.x); cv.h[1] = __float2bfloat16(v.y);
        cv.h[2] = __float2bfloat16(v.z); cv.h[3] = __float2bfloat16(v.w);
        *reinterpret_cast<uint2*>(&aT[0][row][dc]) = cv.u;
        i32x4 wv = *reinterpret_cast<const i32x4*>(&Wp[q * 8]);
        *reinterpret_cast<i32x4*>(&wT[0][q * 8]) = wv;
    }
    __syncthreads();

    int buf = 0;
#pragma unroll
    for (int kk = 0; kk < 8; ++kk) {
        // prefetch next K-chunk into registers
        float4 av[4]; i32x4 wv[4];
        if (kk < 7) {
#pragma unroll
            for (int it = 0; it < 4; ++it) {
                int q = it * 256 + tid;
                int row = q >> 3;
                int dc = (q & 7) * 4;
                av[it] = *reinterpret_cast<const float4*>(
                    &enc[(r0 + row) * H2 + (kk + 1) * 32 + dc]);
                wv[it] = *reinterpret_cast<const i32x4*>(&Wp[(kk + 1) * 8192 + q * 8]);
            }
        }
        // compute on current buffer
        bf16x8 af[2];
#pragma unroll
        for (int rt = 0; rt < 2; ++rt)
            af[rt] = *reinterpret_cast<const bf16x8*>(
                &aT[buf][w * 32 + rt * 16 + (lane & 15)][8 * (lane >> 4)]);
#pragma unroll
        for (int n = 0; n < 16; ++n) {
            bf16x8 bv = *reinterpret_cast<const bf16x8*>(&wT[buf][(n * 64 + lane) * 8]);
            acc[0][n] = __builtin_amdgcn_mfma_f32_16x16x32_bf16(af[0], bv, acc[0][n], 0, 0, 0);
            acc[1][n] = __builtin_amdgcn_mfma_f32_16x16x32_bf16(af[1], bv, acc[1][n], 0, 0, 0);
        }
        // write next chunk to the other buffer
        if (kk < 7) {
#pragma unroll
            for (int it = 0; it < 4; ++it) {
                int q = it * 256 + tid;
                int row = q >> 3;
                int dc = (q & 7) * 4;
                union { __hip_bfloat16 h[4]; uint2 u; } cv;
                cv.h[0] = __float2bfloat16(av[it].x); cv.h[1] = __float2bfloat16(av[it].y);
                cv.h[2] = __float2bfloat16(av[it].z); cv.h[3] = __float2bfloat16(av[it].w);
                *reinterpret_cast<uint2*>(&aT[buf ^ 1][row][dc]) = cv.u;
                *reinterpret_cast<i32x4*>(&wT[buf ^ 1][q * 8]) = wv[it];
            }
        }
        __syncthreads();
        buf ^= 1;
    }

    // ---- epilogue: tanh + proj-dot + 16-lane reduce; fp32 store ----
    // C/D layout: col = n*16 + (lane&15), row = w*32 + rt*16 + (lane>>4)*4 + r
    float biasv[16], projv[16];
#pragma unroll
    for (int n = 0; n < 16; ++n) {
        int e = n * 16 + (lane & 15);
        biasv[n] = bias[e];
        projv[n] = proj[e];
    }
#pragma unroll
    for (int rt = 0; rt < 2; ++rt) {
        float pv[4];
#pragma unroll
        for (int r = 0; r < 4; ++r) {
            float p = 0.0f;
#pragma unroll
            for (int n = 0; n < 16; ++n) {
                float z = acc[rt][n][r] + biasv[n];
                p += projv[n] * fast_tanh(z);
            }
            p += __shfl_xor(p, 1);
            p += __shfl_xor(p, 2);
            p += __shfl_xor(p, 4);
            p += __shfl_xor(p, 8);
            pv[r] = p;
        }
        if ((lane & 15) == 0) {
            long row = r0 + w * 32 + rt * 16 + (lane >> 4) * 4;
            float4 o; o.x = pv[0]; o.y = pv[1]; o.z = pv[2]; o.w = pv[3];
            *reinterpret_cast<float4*>(&attnS[row]) = o;   // [s][b] layout
        }
    }
}

// -------- softmax over s per batch; logits [s][b] -> attn out [b][s] --------
__global__ void r17_softmax(const float* __restrict__ attnS,
                            float* __restrict__ out_attn) {
    __shared__ float sL[SEQ];
    __shared__ float red[256];
    const int b = blockIdx.x;
    const int t = threadIdx.x;

    float lm = -1e30f;
    for (int s = t; s < SEQ; s += 256) {
        float v = attnS[(size_t)s * NB + b];   // strided read, L2-resident
        sL[s] = v;
        lm = fmaxf(lm, v);
    }
    red[t] = lm;
    __syncthreads();
    for (int h = 128; h > 0; h >>= 1) {
        if (t < h) red[t] = fmaxf(red[t], red[t + h]);
        __syncthreads();
    }
    const float gmax = red[0];
    __syncthreads();

    float ls = 0.0f;
    for (int s = t; s < SEQ; s += 256) {
        float e = __expf(sL[s] - gmax);
        sL[s] = e;
        ls += e;
    }
    red[t] = ls;
    __syncthreads();
    for (int h = 128; h > 0; h >>= 1) {
        if (t < h) red[t] += red[t + h];
        __syncthreads();
    }
    const float inv = 1.0f / red[0];

    for (int s = t; s < SEQ; s += 256) {
        out_attn[(size_t)b * SEQ + s] = sL[s] * inv;
    }
}

// -------- partial weighted sums over s-chunks of 256, enc [s][b][d] ---------
__global__ void r17_wsum(const float* __restrict__ enc,
                         const float* __restrict__ out_attn,
                         float* __restrict__ partials) {
    __shared__ float wl[256];
    const int b = blockIdx.x & 63;
    const int c = blockIdx.x >> 6;       // 0..15
    const int t = threadIdx.x;           // = d
    wl[t] = out_attn[(size_t)b * SEQ + c * 256 + t];
    __syncthreads();
    float acc = 0.0f;
    for (int si = 0; si < 256; ++si) {
        acc = fmaf(wl[si],
                   enc[((size_t)(c * 256 + si) * NB + b) * H2 + t],
                   acc);
    }
    partials[((size_t)c * NB + b) * H2 + t] = acc;
}

// -------- final reduce over the 16 chunks; fp32 vectors out -----------------
__global__ void r17_reduce(const float* __restrict__ partials,
                           float* __restrict__ out_vec) {
    const int b = blockIdx.x;
    const int t = threadIdx.x;           // = d
    float a = 0.0f;
    for (int c = 0; c < 16; ++c)
        a += partials[((size_t)c * NB + b) * H2 + t];
    out_vec[(size_t)b * H2 + t] = a;
}

extern "C" void kernel_launch(void* const* d_in, const int* in_sizes, int n_in,
                              void* d_out, int out_size, void* d_ws, size_t ws_size,
                              hipStream_t stream) {
    const float* enc  = (const float*)d_in[0];
    const float* W    = (const float*)d_in[1];
    const float* bias = (const float*)d_in[2];
    const float* proj = (const float*)d_in[3];

    float* out      = (float*)d_out;                 // FLOAT32 outputs
    float* out_vec  = out;                           // [1][64][256]
    float* out_attn = out + NB * H2;                 // [64][4096]

    char* ws = (char*)d_ws;
    __hip_bfloat16* Wp = (__hip_bfloat16*)ws;        // 128 KiB packed W
    float* attnS    = (float*)(ws + 131072);         // 1 MiB fp32 logits [s][b]
    float* partials = (float*)(ws + 131072 + (1u << 20));  // 1 MiB

    hipLaunchKernelGGL(pack_w_kernel,     dim3(32),          dim3(256), 0, stream,
                       W, Wp);
    hipLaunchKernelGGL(mfma_logits_kernel, dim3(MROWS / 128), dim3(256), 0, stream,
                       enc, Wp, bias, proj, attnS);
    hipLaunchKernelGGL(r17_softmax,       dim3(NB),          dim3(256), 0, stream,
                       attnS, out_attn);
    hipLaunchKernelGGL(r17_wsum,          dim3(16 * NB),     dim3(256), 0, stream,
                       enc, out_attn, partials);
    hipLaunchKernelGGL(r17_reduce,        dim3(NB),          dim3(256), 0, stream,
                       partials, out_vec);
}